// Round 8
// baseline (252.103 us; speedup 1.0000x reference)
//
#include <hip/hip_runtime.h>

#define E_DIM 1024
#define NH 16
#define DH 64
#define BSEG 8
#define LQ 512
#define LKV 1024

typedef short bf16x8 __attribute__((ext_vector_type(8)));
typedef float f32x4 __attribute__((ext_vector_type(4)));
typedef unsigned short u16;

// round-to-nearest-even fp32 -> bf16 bits
__device__ __forceinline__ u16 f2bf(float x) {
    unsigned u = __float_as_uint(x);
    u += 0x7FFF + ((u >> 16) & 1);
    return (u16)(u >> 16);
}

// ---------------------------------------------------------------------------
// frag16 canonical layout for a row-major [R,1024] tensor:
//   chunk (t=row>>4, kc=k>>6) of 1024 shorts at ((t*16+kc)*1024);
//   within: ((k&63)>>3)*128 + (row&15)*8 + (k&7).
// MFMA A/B frag (16x16x32) for rows [16t,16t+16), k0: lane l reads 8 shorts
// at chunk + ((k0>>5)&1)*512 + l*8  — one fully-coalesced b128 per frag.
// ---------------------------------------------------------------------------

// cvt v3: fp32 row-major -> bf16 frag16, all 4 tensors in one launch.
// Block = one 16-row tile. Grid 1024: inputs 512 | queries 256 | w_in 192 |
// w_out 64. 16 steps: step s reads row s of the tile (256 float4, coalesced).
__global__ __launch_bounds__(256) void cvt_all_kernel(
    const float* __restrict__ inputs, const float* __restrict__ queries,
    const float* __restrict__ w_in, const float* __restrict__ w_out,
    u16* __restrict__ ifr, u16* __restrict__ qfr,
    u16* __restrict__ wifr, u16* __restrict__ wofr)
{
    int blk = blockIdx.x;
    const float* s; u16* d; int t;
    if (blk < 512)       { s = inputs;  d = ifr;  t = blk; }
    else if (blk < 768)  { s = queries; d = qfr;  t = blk - 512; }
    else if (blk < 960)  { s = w_in;    d = wifr; t = blk - 768; }
    else                 { s = w_out;   d = wofr; t = blk - 960; }
    const int tt = threadIdx.x;
    const int kc = tt >> 4;                 // 0..15
    const int kq = (tt & 15) >> 1;          // 0..7
    const int jo = (tt & 1) * 4;            // 0 or 4
    const float* src = s + (size_t)t * 16 * 1024 + tt * 4;
    u16* dst = d + ((size_t)t * 16 + kc) * 1024 + kq * 128 + jo;
    #pragma unroll
    for (int r = 0; r < 16; ++r) {
        float4 v = *(const float4*)(src + (size_t)r * 1024);
        ushort4 o;
        o.x = f2bf(v.x); o.y = f2bf(v.y); o.z = f2bf(v.z); o.w = f2bf(v.w);
        *(ushort4*)(dst + r * 8) = o;
    }
}

// ---------------------------------------------------------------------------
// Fused Q/K/V projection GEMM v3: NO LDS, NO BARRIERS. 128x128 tile, 4 waves
// x 64x64. Both operands streamed as frag16 b128 loads; compiler pipelines
// with fine-grained vmcnt (no s_barrier drain). XCD-compact grid (r7).
// Grid 1280: KV bid<1024: xcd=bid&7, i=bid>>3, bx=i>>3, by=xcd*8+(i&7);
//   W = w_in frag16 rows [1024,3072) (t offset 64), N=2048.
// Q bid>=1024: i=(bid-1024)>>3, bx=i>>2, by=xcd*4+(i&3); W t offset 0.
// Epilogues (unchanged): Kf/Qf attention-frag16, Vf sigma'-frag.
// ---------------------------------------------------------------------------
__global__ __launch_bounds__(256) void proj_gemm_kernel(
    const u16* __restrict__ Afr_in, const u16* __restrict__ Afr_q,
    const u16* __restrict__ Wfr, const float* __restrict__ b_in,
    u16* __restrict__ Kf, u16* __restrict__ Qf, u16* __restrict__ Vf)
{
    const int bid = blockIdx.x;
    const bool isQ = (bid >= 1024);
    const int x = bid & 7;
    int bx, by;
    if (!isQ) { int i = bid >> 3;          bx = i >> 3; by = x * 8 + (i & 7); }
    else      { int i = (bid - 1024) >> 3; bx = i >> 2; by = x * 4 + (i & 3); }

    const u16* A = isQ ? Afr_q : Afr_in;
    const u16* W = Wfr + (isQ ? 0 : (size_t)64 * 16 * 1024);
    const float* bias = b_in + (isQ ? 0 : E_DIM);
    const int m_blk = by * 128;
    const int n_blk = bx * 128;

    const int tid = threadIdx.x;
    const int l = tid & 63;
    const int w = tid >> 6;
    const int m0 = (w & 1) * 64;
    const int n0 = (w >> 1) * 64;
    const int quad = l >> 4;
    const int c = l & 15;

    const int tA = (m_blk + m0) >> 4;     // A chunk-t base (4 tiles)
    const int tW = (n_blk + n0) >> 4;     // W chunk-t base (4 tiles)

    f32x4 acc[4][4];
    #pragma unroll
    for (int i = 0; i < 4; ++i)
        #pragma unroll
        for (int j = 0; j < 4; ++j)
            acc[i][j] = (f32x4){0.f, 0.f, 0.f, 0.f};

    const u16* Ab = A + (size_t)l * 8;
    const u16* Wb = W + (size_t)l * 8;

    for (int kc = 0; kc < 16; ++kc) {
        #pragma unroll
        for (int kh = 0; kh < 2; ++kh) {
            bf16x8 af[4], wf[4];
            #pragma unroll
            for (int i = 0; i < 4; ++i)
                af[i] = *(const bf16x8*)(Ab + ((size_t)(tA + i) * 16 + kc) * 1024 + kh * 512);
            #pragma unroll
            for (int j = 0; j < 4; ++j)
                wf[j] = *(const bf16x8*)(Wb + ((size_t)(tW + j) * 16 + kc) * 1024 + kh * 512);
            #pragma unroll
            for (int i = 0; i < 4; ++i)
                #pragma unroll
                for (int j = 0; j < 4; ++j)
                    acc[i][j] = __builtin_amdgcn_mfma_f32_16x16x32_bf16(
                        af[i], wf[j], acc[i][j], 0, 0, 0);
        }
    }

    #pragma unroll
    for (int jj = 0; jj < 4; ++jj) {
        int col = n_blk + n0 + jj * 16 + c;
        float bv = bias[col];
        if (isQ || col < 1024) {
            u16* dst = isQ ? Qf : Kf;
            int hh = col >> 6, d = col & 63;
            int dq = d >> 3, dj = d & 7;
            #pragma unroll
            for (int i = 0; i < 4; ++i) {
                int t = (m_blk + m0 + i * 16) >> 4;
                size_t base = ((size_t)(t * NH + hh)) * 1024
                            + (size_t)(dq * 16 + quad * 4) * 8 + dj;
                #pragma unroll
                for (int r = 0; r < 4; ++r)
                    dst[base + (size_t)r * 8] = f2bf(acc[i][jj][r] + bv);
            }
        } else {
            int vcol = col - 1024;
            int hv = vcol >> 6, d = vcol & 63;
            int td = d >> 4, ct = d & 15;
            #pragma unroll
            for (int i = 0; i < 4; ++i) {
                int tok = m_blk + m0 + i * 16;
                int g32 = tok >> 5;
                int jo = (tok & 16) >> 2;          // 0 or 4
                ushort4 pk;
                pk.x = f2bf(acc[i][jj][0] + bv);
                pk.y = f2bf(acc[i][jj][1] + bv);
                pk.z = f2bf(acc[i][jj][2] + bv);
                pk.w = f2bf(acc[i][jj][3] + bv);
                *(ushort4*)(Vf + ((size_t)(g32 * NH + hv)) * 2048
                            + (size_t)((td * 4 + quad) * 16 + ct) * 8 + jo) = pk;
            }
        }
    }
}

// ---------------------------------------------------------------------------
// Attention, S^T formulation; frag-ordered operands; no LDS/barriers.
// 1D grid 1024: bid = qt*128 + b*16 + h -> bid%8 = h%8 (XCD shares K/V).
// Epilogue now writes Ob in frag16 (for the streaming out_gemm).
// ---------------------------------------------------------------------------
struct KVfrags { bf16x8 kf[4][2]; bf16x8 vf[2][4]; };

__global__ __launch_bounds__(256) void attn_kernel(
    const u16* __restrict__ Qf, const u16* __restrict__ Kf,
    const u16* __restrict__ Vf, u16* __restrict__ Obf)
{
    const int tid = threadIdx.x;
    const int l = tid & 63;
    const int w = tid >> 6;
    const int quad = l >> 4;
    const int c = l & 15;
    const int bid = blockIdx.x;
    const int h = bid & 15;
    const int b = (bid >> 4) & 7;
    const int qt = bid >> 7;
    const int q0 = b * LQ + qt * 64 + w * 16;
    const float C1 = 0.18033688011112042f;   // (1/8)*log2(e)

    bf16x8 qf[2];
    {
        size_t qb = ((size_t)((q0 >> 4) * NH + h)) * 1024 + (size_t)l * 8;
        qf[0] = *(const bf16x8*)(Qf + qb);
        qf[1] = *(const bf16x8*)(Qf + qb + 512);
    }

    f32x4 o[4];
    #pragma unroll
    for (int td = 0; td < 4; ++td) o[td] = (f32x4){0.f, 0.f, 0.f, 0.f};
    float m_i = -1e30f, l_i = 0.f;

    auto load_kv = [&](int kv0, KVfrags& dst) {
        const int kvg = b * LKV + kv0;
        #pragma unroll
        for (int nt = 0; nt < 4; ++nt) {
            size_t kb = ((size_t)((((kvg >> 4) + nt) * NH) + h)) * 1024 + (size_t)l * 8;
            dst.kf[nt][0] = *(const bf16x8*)(Kf + kb);
            dst.kf[nt][1] = *(const bf16x8*)(Kf + kb + 512);
        }
        #pragma unroll
        for (int g = 0; g < 2; ++g) {
            size_t vb = ((size_t)((((kvg >> 5) + g) * NH) + h)) * 2048 + (size_t)l * 8;
            #pragma unroll
            for (int td = 0; td < 4; ++td)
                dst.vf[g][td] = *(const bf16x8*)(Vf + vb + td * 512);
        }
    };

    auto step = [&](KVfrags& cv) {
        f32x4 s[4];
        #pragma unroll
        for (int nt = 0; nt < 4; ++nt) s[nt] = (f32x4){0.f, 0.f, 0.f, 0.f};
        #pragma unroll
        for (int nt = 0; nt < 4; ++nt)
            #pragma unroll
            for (int hk = 0; hk < 2; ++hk)
                s[nt] = __builtin_amdgcn_mfma_f32_16x16x32_bf16(
                    cv.kf[nt][hk], qf[hk], s[nt], 0, 0, 0);

        float vm = -1e30f;
        #pragma unroll
        for (int nt = 0; nt < 4; ++nt)
            #pragma unroll
            for (int r = 0; r < 4; ++r) vm = fmaxf(vm, s[nt][r]);
        vm = fmaxf(vm, __shfl_xor(vm, 16, 64));
        vm = fmaxf(vm, __shfl_xor(vm, 32, 64));
        float mnew = fmaxf(m_i, vm);
        float alpha = __builtin_amdgcn_exp2f((m_i - mnew) * C1);
        m_i = mnew;

        float p[4][4];
        float rs = 0.f;
        #pragma unroll
        for (int nt = 0; nt < 4; ++nt)
            #pragma unroll
            for (int r = 0; r < 4; ++r) {
                p[nt][r] = __builtin_amdgcn_exp2f((s[nt][r] - mnew) * C1);
                rs += p[nt][r];
            }
        rs += __shfl_xor(rs, 16, 64);
        rs += __shfl_xor(rs, 32, 64);
        l_i = l_i * alpha + rs;

        float ar[4];
        #pragma unroll
        for (int r = 0; r < 4; ++r) ar[r] = __shfl(alpha, quad * 4 + r, 16);
        #pragma unroll
        for (int td = 0; td < 4; ++td)
            #pragma unroll
            for (int r = 0; r < 4; ++r) o[td][r] *= ar[r];

        bf16x8 af[2];
        #pragma unroll
        for (int g = 0; g < 2; ++g)
            #pragma unroll
            for (int r = 0; r < 4; ++r) {
                af[g][r]     = (short)f2bf(p[2 * g][r]);
                af[g][4 + r] = (short)f2bf(p[2 * g + 1][r]);
            }

        #pragma unroll
        for (int g = 0; g < 2; ++g)
            #pragma unroll
            for (int td = 0; td < 4; ++td)
                o[td] = __builtin_amdgcn_mfma_f32_16x16x32_bf16(
                    af[g], cv.vf[g][td], o[td], 0, 0, 0);
    };

    KVfrags bufA, bufB;
    load_kv(0, bufA);
    #pragma unroll
    for (int it = 0; it < 16; it += 2) {
        if (it + 1 < 16) load_kv((it + 1) * 64, bufB);
        step(bufA);
        if (it + 2 < 16) load_kv((it + 2) * 64, bufA);
        if (it + 1 < 16) step(bufB);
    }

    // epilogue: normalize, store Ob in frag16 (rows=tokens, k=E):
    // idx = ((row>>4)*16 + h)*1024 + ((k&63)>>3)*128 + (row&15)*8 + (k&7),
    // k = h*64 + td*16 + c, row = q0 + quad*4 + r  (q0 is 16-aligned).
    float invl = 1.f / l_i;
    float ir[4];
    #pragma unroll
    for (int r = 0; r < 4; ++r) ir[r] = __shfl(invl, quad * 4 + r, 16);
    size_t obase = ((size_t)((q0 >> 4) * 16 + h)) * 1024;
    #pragma unroll
    for (int td = 0; td < 4; ++td) {
        size_t kpart = (size_t)(td * 2 + (c >> 3)) * 128 + (c & 7);
        #pragma unroll
        for (int r = 0; r < 4; ++r)
            Obf[obase + kpart + (size_t)(quad * 4 + r) * 8] =
                f2bf(o[td][r] * ir[r]);
    }
}

// ---------------------------------------------------------------------------
// Output projection v3: NO LDS, NO BARRIERS. A = Obf frag16, W = w_out frag16.
// out[4096,1024] fp32 row-major. 1D grid 256, XCD-compact.
// ---------------------------------------------------------------------------
__global__ __launch_bounds__(256) void out_gemm_kernel(
    const u16* __restrict__ Afr, const u16* __restrict__ Wfr,
    const float* __restrict__ bias, float* __restrict__ Cf)
{
    const int N = E_DIM;
    const int bid = blockIdx.x;
    const int x = bid & 7;
    const int i_ = bid >> 3;
    const int m_blk = (x * 4 + (i_ & 3)) * 128;
    const int n_blk = (i_ >> 2) * 128;

    const int tid = threadIdx.x;
    const int l = tid & 63;
    const int w = tid >> 6;
    const int m0 = (w & 1) * 64;
    const int n0 = (w >> 1) * 64;
    const int quad = l >> 4;
    const int c = l & 15;

    const int tA = (m_blk + m0) >> 4;
    const int tW = (n_blk + n0) >> 4;

    f32x4 acc[4][4];
    #pragma unroll
    for (int i = 0; i < 4; ++i)
        #pragma unroll
        for (int j = 0; j < 4; ++j)
            acc[i][j] = (f32x4){0.f, 0.f, 0.f, 0.f};

    const u16* Ab = Afr + (size_t)l * 8;
    const u16* Wb = Wfr + (size_t)l * 8;

    for (int kc = 0; kc < 16; ++kc) {
        #pragma unroll
        for (int kh = 0; kh < 2; ++kh) {
            bf16x8 af[4], wf[4];
            #pragma unroll
            for (int i = 0; i < 4; ++i)
                af[i] = *(const bf16x8*)(Ab + ((size_t)(tA + i) * 16 + kc) * 1024 + kh * 512);
            #pragma unroll
            for (int j = 0; j < 4; ++j)
                wf[j] = *(const bf16x8*)(Wb + ((size_t)(tW + j) * 16 + kc) * 1024 + kh * 512);
            #pragma unroll
            for (int i = 0; i < 4; ++i)
                #pragma unroll
                for (int j = 0; j < 4; ++j)
                    acc[i][j] = __builtin_amdgcn_mfma_f32_16x16x32_bf16(
                        af[i], wf[j], acc[i][j], 0, 0, 0);
        }
    }

    #pragma unroll
    for (int j = 0; j < 4; ++j) {
        int col = n_blk + n0 + j * 16 + c;
        float bv = bias[col];
        #pragma unroll
        for (int i = 0; i < 4; ++i) {
            int row = m_blk + m0 + i * 16 + quad * 4;
            #pragma unroll
            for (int r = 0; r < 4; ++r)
                Cf[(size_t)(row + r) * N + col] = acc[i][j][r] + bv;
        }
    }
}

// ---------------------------------------------------------------------------
extern "C" void kernel_launch(void* const* d_in, const int* in_sizes, int n_in,
                              void* d_out, int out_size, void* d_ws, size_t ws_size,
                              hipStream_t stream) {
    const float* inputs  = (const float*)d_in[0];   // [8192,1024]
    const float* queries = (const float*)d_in[1];   // [4096,1024]
    const float* w_in    = (const float*)d_in[2];   // [3072,1024]
    const float* b_in    = (const float*)d_in[3];   // [3072]
    const float* w_out   = (const float*)d_in[4];   // [1024,1024]
    const float* b_out   = (const float*)d_in[5];   // [1024]
    float* out = (float*)d_out;                     // [4096,1024] fp32

    const int NQ = BSEG * LQ;    // 4096
    const int NKV = BSEG * LKV;  // 8192

    // workspace: 80 MB (all bf16)
    u16* inputs_f  = (u16*)d_ws;                                   // 16 MB
    u16* queries_f = inputs_f  + (size_t)NKV * E_DIM;              //  8 MB
    u16* w_in_f    = queries_f + (size_t)NQ * E_DIM;               //  6 MB
    u16* w_out_f   = w_in_f    + (size_t)3 * E_DIM * E_DIM;        //  2 MB
    u16* Qf        = w_out_f   + (size_t)E_DIM * E_DIM;            //  8 MB
    u16* Kf        = Qf        + (size_t)NQ * E_DIM;               // 16 MB
    u16* Vf        = Kf        + (size_t)NKV * E_DIM;              // 16 MB
    u16* Obf       = Vf        + (size_t)NKV * E_DIM;              //  8 MB

    dim3 blk(256);

    cvt_all_kernel<<<1024, blk, 0, stream>>>(
        inputs, queries, w_in, w_out, inputs_f, queries_f, w_in_f, w_out_f);

    proj_gemm_kernel<<<1280, blk, 0, stream>>>(
        inputs_f, queries_f, w_in_f, b_in, Kf, Qf, Vf);

    attn_kernel<<<1024, blk, 0, stream>>>(Qf, Kf, Vf, Obf);

    out_gemm_kernel<<<256, blk, 0, stream>>>(
        Obf, w_out_f, b_out, out);
}